// Round 20
// baseline (110.961 us; speedup 1.0000x reference)
//
#include <hip/hip_runtime.h>

#define B 8
#define N 512
#define D 128
#define H 128
#define IC 8      // valid-i rows per block (pair kernel)
#define JT 64     // valid-j cols per block (4 waves x 16)
#define NF 1024   // fill blocks in prep kernel

typedef __attribute__((ext_vector_type(8))) _Float16 f16x8;
typedef __attribute__((ext_vector_type(4))) float f32x4;

union F8 { uint4 u; f16x8 f; };

// W2-row permutation for the reduce-MFMA epilogue:
// pi(g,m) = (g>=2)*32 + (m>>2)*8 + (g&1)*4 + (m&3)
__device__ __host__ inline int w2perm(int g, int m) {
    return ((g >> 1) << 5) + ((m >> 2) << 3) + ((g & 1) << 2) + (m & 3);
}

// ---------------- kernel A: prep = fill(out) + build weights + scan ----------------
__global__ __launch_bounds__(256) void prep_kernel(
        const float* __restrict__ W1, const float* __restrict__ W2,
        const float* __restrict__ b1, const float* __restrict__ b2,
        const float* __restrict__ W3, const int* __restrict__ mask,
        float4* __restrict__ out4,
        _Float16* __restrict__ Wpq, _Float16* __restrict__ W2h,
        float* __restrict__ b1e, float* __restrict__ b2p,
        _Float16* __restrict__ w3h,
        int* __restrict__ idx, int* __restrict__ cnt) {
    int blk = blockIdx.x;
    int tid = threadIdx.x;
    if (blk < NF) {
        // zero-fill output: 2M float4 over 1024 blocks -> 2 per thread
        int base = blk * 512 + tid;
        out4[base]       = float4{0.f, 0.f, 0.f, 0.f};
        out4[base + 256] = float4{0.f, 0.f, 0.f, 0.f};
    } else if (blk < NF + 64) {
        int t = (blk - NF) * 256 + tid;   // 0 .. 16383
        if (t < H * D) {
            int h = t >> 7, k = t & 127;
            float wa = W1[h * 384 + k];
            float wb = W1[h * 384 + 128 + k];
            float wc = W1[h * 384 + 256 + k];
            Wpq[h * 128 + k]         = (_Float16)(wa + wc);
            Wpq[(128 + h) * 128 + k] = (_Float16)(wb - wc);
        }
        if (t < 64 * H) {   // permuted W2 rows
            int on = t >> 7, k = t & 127;
            int pi = w2perm(on >> 4, on & 15);
            W2h[t] = (_Float16)W2[pi * 128 + k];
        }
        if (t < 256) b1e[t] = (t < 128) ? b1[t] : 0.f;
        if (t < 64) {
            int pi = w2perm(t >> 4, t & 15);
            b2p[t] = b2[pi];
            w3h[t] = (_Float16)W3[t];
        }
    } else {
        int b = blk - NF - 64;
        int lane = tid;
        if (lane >= 64) return;
        const int* m = mask + b * N;
        int base = 0;
        for (int ch = 0; ch < N / 64; ++ch) {
            int v = m[ch * 64 + lane];
            unsigned long long bal = __ballot(v != 0);
            int pos = base + __popcll(bal & ((1ull << lane) - 1ull));
            if (v) idx[b * N + pos] = ch * 64 + lane;
            base += __popcll(bal);
        }
        if (lane == 0) cnt[b] = base;
    }
}

// ---------------- kernel 2: PQ = f16( F0 @ Wpq^T + b1e ), coalesced stores ----------------
__global__ __launch_bounds__(64) void pq_mfma_kernel(const float* __restrict__ F0,
                                                     const _Float16* __restrict__ Wpq,
                                                     const float* __restrict__ b1e,
                                                     _Float16* __restrict__ PQ) {
    int r0 = blockIdx.x * 16;        // F0 row base
    int cb = blockIdx.y * 64;        // output col base
    int lane = threadIdx.x;
    int lp = lane & 15, lg = lane >> 4;

    __shared__ _Float16 T[16][64];   // 2 KB transpose staging

    f16x8 af[4];
    const float* fr = F0 + (size_t)(r0 + lp) * D;
#pragma unroll
    for (int ks = 0; ks < 4; ++ks) {
        float4 a0 = *(const float4*)(fr + ks * 32 + lg * 8);
        float4 a1 = *(const float4*)(fr + ks * 32 + lg * 8 + 4);
        f16x8 v;
        v[0] = (_Float16)a0.x; v[1] = (_Float16)a0.y;
        v[2] = (_Float16)a0.z; v[3] = (_Float16)a0.w;
        v[4] = (_Float16)a1.x; v[5] = (_Float16)a1.y;
        v[6] = (_Float16)a1.z; v[7] = (_Float16)a1.w;
        af[ks] = v;
    }

#pragma unroll
    for (int ct = 0; ct < 4; ++ct) {
        int col = cb + ct * 16 + lp;
        const _Float16* wrow = Wpq + (size_t)col * 128;
        f32x4 acc = 0.f;
#pragma unroll
        for (int ks = 0; ks < 4; ++ks) {
            f16x8 bf = *(const f16x8*)(wrow + ks * 32 + lg * 8);
            acc = __builtin_amdgcn_mfma_f32_16x16x32_f16(af[ks], bf, acc, 0, 0, 0);
        }
        float b1v = b1e[col];
#pragma unroll
        for (int e = 0; e < 4; ++e)
            T[lg * 4 + e][ct * 16 + lp] = (_Float16)(acc[e] + b1v);
    }
    __syncthreads();

    // coalesced store: 4 lanes per row, 32B each -> 128B/row contiguous
    int r  = lane >> 2;
    int c4 = (lane & 3) * 16;
    uint4 v0 = *(const uint4*)&T[r][c4];
    uint4 v1 = *(const uint4*)&T[r][c4 + 8];
    _Float16* dst = PQ + (size_t)(r0 + r) * 256 + cb + c4;
    *(uint4*)dst       = v0;
    *(uint4*)(dst + 8) = v1;
}

// ---------------- kernel 3: fused pair MLP; W2 in swizzled LDS; single-ii; (256,4) ----------------
// Register budget engineered for the 128-reg cap: no w2f (LDS), no dual-ii
// (acc=16). IC=8 -> 1024 active blocks = 4/CU x 4 waves = 4 waves/SIMD.
__global__ __launch_bounds__(256, 4) void pair_mfma_kernel(
        const _Float16* __restrict__ PQ,
        const _Float16* __restrict__ W2h,
        const float* __restrict__ b2p, const _Float16* __restrict__ w3h,
        const float* __restrict__ b3v,
        const int* __restrict__ idx, const int* __restrict__ cnt,
        float* __restrict__ out) {
    int t = blockIdx.x;
    // map flat tile id -> (b, i0, j0) via per-batch tile counts from cnt[]
    int b = -1, local = 0, nv = 0, acc = 0;
#pragma unroll
    for (int k = 0; k < B; ++k) {
        int c   = cnt[k];
        int nTi = (c + IC - 1) / IC;
        int nTj = (c + JT - 1) / JT;
        int tl  = nTi * nTj;
        if (b < 0 && t < acc + tl) { b = k; local = t - acc; nv = c; }
        acc += tl;
    }
    if (b < 0) return;                 // contiguous dead tail
    int nTj = (nv + JT - 1) / JT;
    int i0  = (local / nTj) * IC;
    int j0  = (local % nTj) * JT;

    int tid  = threadIdx.x;
    int lane = tid & 63;
    int w    = tid >> 6;          // wave 0..3
    int lg   = lane >> 4;         // k-slice group 0..3
    int lp   = lane & 15;         // pair col / row-within-group

    __shared__ uint4 W2s[64][16]; // 16 KB, unit-swizzled: [row][u ^ (row&15)]
    __shared__ uint4 Pl[IC][16];  // P rows (compacted) as f16
    __shared__ int   iI[IC];      // original row index per compacted i

    {   // stage W2 (1024 uint4), coalesced global read, swizzled LDS write
        const uint4* W2v = (const uint4*)W2h;
#pragma unroll
        for (int q = 0; q < 4; ++q) {
            int m = tid + q * 256;
            int r = m >> 4, u = m & 15;
            W2s[r][u ^ (r & 15)] = W2v[m];
        }
    }
    if (tid < IC * 16) {
        int r = tid >> 4, c = tid & 15;
        int ir = i0 + r;
        int ivr = idx[b * N + (ir < nv ? ir : nv - 1)];
        if (c == 0) iI[r] = ivr;
        Pl[r][c] = *(const uint4*)(PQ + ((size_t)(b * N) + ivr) * 256 + c * 8);
    }
    __syncthreads();

    // per-c W2 read pointers: row = g*16+lp, unit = (c*4+lg)^lp; g via +g*256 units
    const uint4* pw0 = &W2s[lp][(0 * 4 + lg) ^ lp];
    const uint4* pw1 = &W2s[lp][(1 * 4 + lg) ^ lp];
    const uint4* pw2 = &W2s[lp][(2 * 4 + lg) ^ lp];
    const uint4* pw3 = &W2s[lp][(3 * 4 + lg) ^ lp];

    // Q fragments: lane's compacted pair jj = j0 + w*16 + lp
    int jj   = j0 + w * 16 + lp;
    bool jok = jj < nv;
    int jidx = idx[b * N + (jok ? jj : nv - 1)];
    F8 qf[4];
    {
        const _Float16* qrow = PQ + ((size_t)(b * N) + jidx) * 256 + 128;
#pragma unroll
        for (int c = 0; c < 4; ++c)
            qf[c].u = *(const uint4*)(qrow + c * 32 + lg * 8);
    }

    // epilogue constants
    f32x4 b2v[4];
#pragma unroll
    for (int g = 0; g < 4; ++g)
        b2v[g] = *(const f32x4*)(b2p + g * 16 + lg * 4);
    f16x8 w3f0 = *(const f16x8*)(w3h + lg * 8);
    f16x8 w3f1 = *(const f16x8*)(w3h + 32 + lg * 8);
    float b3s = b3v[0];
    const f32x4 z4 = 0.f;
    const f16x8 zh = (f16x8)(_Float16)0;

    size_t outbase = ((size_t)(b * N)) * N;

#define CSTEP(ACC, II, C, PW)                                                  \
    {                                                                          \
        F8 ph; ph.u = Pl[II][(C) * 4 + lg];                                    \
        f16x8 hv = __builtin_elementwise_max(ph.f + qf[C].f, zh);              \
        F8 a0, a1, a2, a3;                                                     \
        a0.u = PW[0 * 256]; a1.u = PW[1 * 256];                                \
        a2.u = PW[2 * 256]; a3.u = PW[3 * 256];                                \
        ACC[0] = __builtin_amdgcn_mfma_f32_16x16x32_f16(a0.f, hv, ACC[0], 0, 0, 0); \
        ACC[1] = __builtin_amdgcn_mfma_f32_16x16x32_f16(a1.f, hv, ACC[1], 0, 0, 0); \
        ACC[2] = __builtin_amdgcn_mfma_f32_16x16x32_f16(a2.f, hv, ACC[2], 0, 0, 0); \
        ACC[3] = __builtin_amdgcn_mfma_f32_16x16x32_f16(a3.f, hv, ACC[3], 0, 0, 0); \
    }

// independent reduce-MFMAs (rac0 || rac1), summed at the end
#define EPI(ACC, II)                                                           \
    {                                                                          \
        f32x4 t0 = __builtin_elementwise_max(ACC[0] + b2v[0], z4);             \
        f32x4 t1 = __builtin_elementwise_max(ACC[1] + b2v[1], z4);             \
        f32x4 t2 = __builtin_elementwise_max(ACC[2] + b2v[2], z4);             \
        f32x4 t3 = __builtin_elementwise_max(ACC[3] + b2v[3], z4);             \
        f16x8 h0, h1;                                                          \
        h0[0] = (_Float16)t0[0]; h0[1] = (_Float16)t0[1];                      \
        h0[2] = (_Float16)t0[2]; h0[3] = (_Float16)t0[3];                      \
        h0[4] = (_Float16)t1[0]; h0[5] = (_Float16)t1[1];                      \
        h0[6] = (_Float16)t1[2]; h0[7] = (_Float16)t1[3];                      \
        h1[0] = (_Float16)t2[0]; h1[1] = (_Float16)t2[1];                      \
        h1[2] = (_Float16)t2[2]; h1[3] = (_Float16)t2[3];                      \
        h1[4] = (_Float16)t3[0]; h1[5] = (_Float16)t3[1];                      \
        h1[6] = (_Float16)t3[2]; h1[7] = (_Float16)t3[3];                      \
        f32x4 rac0 = {b3s, b3s, b3s, b3s};                                     \
        f32x4 rac1 = 0.f;                                                      \
        rac0 = __builtin_amdgcn_mfma_f32_16x16x32_f16(w3f0, h0, rac0, 0, 0, 0);\
        rac1 = __builtin_amdgcn_mfma_f32_16x16x32_f16(w3f1, h1, rac1, 0, 0, 0);\
        float logit = rac0[0] + rac1[0];                                       \
        float val = 1.f / (1.f + __expf(-logit));                              \
        if (lane < 16 && jok && (i0 + (II)) < nv)                              \
            out[outbase + (size_t)iI[II] * N + jidx] = val;                    \
    }

    f32x4 accA[4], accB[4];
#pragma unroll 1
    for (int ii = 0; ii < IC; ii += 2) {
#pragma unroll
        for (int g = 0; g < 4; ++g) { accA[g] = 0.f; accB[g] = 0.f; }
        CSTEP(accA, ii, 0, pw0)
        CSTEP(accA, ii, 1, pw1)
        CSTEP(accA, ii, 2, pw2)
        CSTEP(accA, ii, 3, pw3)
        CSTEP(accB, ii + 1, 0, pw0)
        CSTEP(accB, ii + 1, 1, pw1)
        CSTEP(accB, ii + 1, 2, pw2)
        CSTEP(accB, ii + 1, 3, pw3)
        EPI(accA, ii)
        EPI(accB, ii + 1)
    }

#undef CSTEP
#undef EPI
}

extern "C" void kernel_launch(void* const* d_in, const int* in_sizes, int n_in,
                              void* d_out, int out_size, void* d_ws, size_t ws_size,
                              hipStream_t stream) {
    const float* F0  = (const float*)d_in[0];
    const int*   msk = (const int*)  d_in[1];
    const float* W1  = (const float*)d_in[2];
    const float* b1  = (const float*)d_in[3];
    const float* W2  = (const float*)d_in[4];
    const float* b2  = (const float*)d_in[5];
    const float* W3  = (const float*)d_in[6];
    const float* b3  = (const float*)d_in[7];
    float* out = (float*)d_out;

    char* ws = (char*)d_ws;
    _Float16* PQ  = (_Float16*)ws;                                   // 2 MB
    _Float16* Wpq = (_Float16*)(ws + (2u << 20));                    // 64 KB
    _Float16* W2h = (_Float16*)(ws + (2u << 20) + (64u << 10));      // 16 KB
    float*    b1e = (float*)   (ws + (2u << 20) + (80u << 10));      // 1 KB
    float*    b2p = (float*)   (ws + (2u << 20) + (81u << 10));      // 256 B
    _Float16* w3h = (_Float16*)(ws + (2u << 20) + (82u << 10));      // 128 B
    int*      idx = (int*)     (ws + (2u << 20) + (84u << 10));      // 16 KB
    int*      cnt = (int*)     (ws + (2u << 20) + (100u << 10));     // 64 B

    // prep: zero output (masked pairs -> sigmoid(-1e9)==0), build weights, scan mask
    prep_kernel<<<NF + 64 + 8, 256, 0, stream>>>(W1, W2, b1, b2, W3, msk,
                                                 (float4*)out, Wpq, W2h, b1e, b2p,
                                                 w3h, idx, cnt);
    pq_mfma_kernel<<<dim3(B * N / 16, 4), 64, 0, stream>>>(F0, Wpq, b1e, PQ);

    int maxTiles = B * ((N + IC - 1) / IC) * ((N + JT - 1) / JT);    // 4096
    pair_mfma_kernel<<<maxTiles, 256, 0, stream>>>(
        PQ, W2h, b2p, w3h, b3, idx, cnt, out);
}

// Round 21
// 37.351 us; speedup vs baseline: 2.9707x; 2.9707x over previous
//
#include <hip/hip_runtime.h>

#define B 8
#define N 512
#define D 128
#define H 128
#define IC 16     // valid-i rows per block (pair kernel)
#define JT 64     // valid-j cols per block (4 waves x 16)
#define NF 1024   // fill blocks in prep kernel

typedef __attribute__((ext_vector_type(8))) _Float16 f16x8;
typedef __attribute__((ext_vector_type(4))) float f32x4;

union F8 { uint4 u; f16x8 f; };

// W2-row permutation for the reduce-MFMA epilogue:
// pi(g,m) = (g>=2)*32 + (m>>2)*8 + (g&1)*4 + (m&3)
__device__ __host__ inline int w2perm(int g, int m) {
    return ((g >> 1) << 5) + ((m >> 2) << 3) + ((g & 1) << 2) + (m & 3);
}

// ---------------- kernel A: prep = fill(out) + build weights + scan ----------------
__global__ __launch_bounds__(256) void prep_kernel(
        const float* __restrict__ W1, const float* __restrict__ W2,
        const float* __restrict__ b1, const float* __restrict__ b2,
        const float* __restrict__ W3, const int* __restrict__ mask,
        float4* __restrict__ out4,
        _Float16* __restrict__ Wpq, _Float16* __restrict__ W2h,
        float* __restrict__ b1e, float* __restrict__ b2p,
        _Float16* __restrict__ w3h,
        int* __restrict__ idx, int* __restrict__ cnt) {
    int blk = blockIdx.x;
    int tid = threadIdx.x;
    if (blk < NF) {
        int base = blk * 512 + tid;
        out4[base]       = float4{0.f, 0.f, 0.f, 0.f};
        out4[base + 256] = float4{0.f, 0.f, 0.f, 0.f};
    } else if (blk < NF + 64) {
        int t = (blk - NF) * 256 + tid;   // 0 .. 16383
        if (t < H * D) {
            int h = t >> 7, k = t & 127;
            float wa = W1[h * 384 + k];
            float wb = W1[h * 384 + 128 + k];
            float wc = W1[h * 384 + 256 + k];
            Wpq[h * 128 + k]         = (_Float16)(wa + wc);
            Wpq[(128 + h) * 128 + k] = (_Float16)(wb - wc);
        }
        if (t < 64 * H) {   // permuted W2 rows
            int on = t >> 7, k = t & 127;
            int pi = w2perm(on >> 4, on & 15);
            W2h[t] = (_Float16)W2[pi * 128 + k];
        }
        if (t < 256) b1e[t] = (t < 128) ? b1[t] : 0.f;
        if (t < 64) {
            int pi = w2perm(t >> 4, t & 15);
            b2p[t] = b2[pi];
            w3h[t] = (_Float16)W3[t];
        }
    } else {
        int b = blk - NF - 64;
        int lane = tid;
        if (lane >= 64) return;
        const int* m = mask + b * N;
        int base = 0;
        for (int ch = 0; ch < N / 64; ++ch) {
            int v = m[ch * 64 + lane];
            unsigned long long bal = __ballot(v != 0);
            int pos = base + __popcll(bal & ((1ull << lane) - 1ull));
            if (v) idx[b * N + pos] = ch * 64 + lane;
            base += __popcll(bal);
        }
        if (lane == 0) cnt[b] = base;
    }
}

// ---------------- kernel 2: PQ = f16( F0 @ Wpq^T + b1e ), coalesced stores ----------------
__global__ __launch_bounds__(64) void pq_mfma_kernel(const float* __restrict__ F0,
                                                     const _Float16* __restrict__ Wpq,
                                                     const float* __restrict__ b1e,
                                                     _Float16* __restrict__ PQ) {
    int r0 = blockIdx.x * 16;        // F0 row base
    int cb = blockIdx.y * 64;        // output col base
    int lane = threadIdx.x;
    int lp = lane & 15, lg = lane >> 4;

    __shared__ _Float16 T[16][64];   // 2 KB transpose staging

    f16x8 af[4];
    const float* fr = F0 + (size_t)(r0 + lp) * D;
#pragma unroll
    for (int ks = 0; ks < 4; ++ks) {
        float4 a0 = *(const float4*)(fr + ks * 32 + lg * 8);
        float4 a1 = *(const float4*)(fr + ks * 32 + lg * 8 + 4);
        f16x8 v;
        v[0] = (_Float16)a0.x; v[1] = (_Float16)a0.y;
        v[2] = (_Float16)a0.z; v[3] = (_Float16)a0.w;
        v[4] = (_Float16)a1.x; v[5] = (_Float16)a1.y;
        v[6] = (_Float16)a1.z; v[7] = (_Float16)a1.w;
        af[ks] = v;
    }

#pragma unroll
    for (int ct = 0; ct < 4; ++ct) {
        int col = cb + ct * 16 + lp;
        const _Float16* wrow = Wpq + (size_t)col * 128;
        f32x4 acc = 0.f;
#pragma unroll
        for (int ks = 0; ks < 4; ++ks) {
            f16x8 bf = *(const f16x8*)(wrow + ks * 32 + lg * 8);
            acc = __builtin_amdgcn_mfma_f32_16x16x32_f16(af[ks], bf, acc, 0, 0, 0);
        }
        float b1v = b1e[col];
#pragma unroll
        for (int e = 0; e < 4; ++e)
            T[lg * 4 + e][ct * 16 + lp] = (_Float16)(acc[e] + b1v);
    }
    __syncthreads();

    // coalesced store: 4 lanes per row, 32B each -> 128B/row contiguous
    int r  = lane >> 2;
    int c4 = (lane & 3) * 16;
    uint4 v0 = *(const uint4*)&T[r][c4];
    uint4 v1 = *(const uint4*)&T[r][c4 + 8];
    _Float16* dst = PQ + (size_t)(r0 + r) * 256 + cb + c4;
    *(uint4*)dst       = v0;
    *(uint4*)(dst + 8) = v1;
}

// ---------------- kernel 3: fused pair MLP; full unroll; deferred sigmoid+store ----------------
// (256,3): the proven no-spill operating point ((256,4) spills -- R8/R17/R20).
// Full ii-unroll (compile-time indices) lets the scheduler hoist next-iteration
// LDS reads into EPI latency shadows; sigmoid+store batched post-loop.
__global__ __launch_bounds__(256, 3) void pair_mfma_kernel(
        const _Float16* __restrict__ PQ,
        const _Float16* __restrict__ W2h,
        const float* __restrict__ b2p, const _Float16* __restrict__ w3h,
        const float* __restrict__ b3v,
        const int* __restrict__ idx, const int* __restrict__ cnt,
        float* __restrict__ out) {
    int t = blockIdx.x;
    // map flat tile id -> (b, i0, j0) via per-batch tile counts from cnt[]
    int b = -1, local = 0, nv = 0, acc = 0;
#pragma unroll
    for (int k = 0; k < B; ++k) {
        int c   = cnt[k];
        int nTi = (c + IC - 1) / IC;
        int nTj = (c + JT - 1) / JT;
        int tl  = nTi * nTj;
        if (b < 0 && t < acc + tl) { b = k; local = t - acc; nv = c; }
        acc += tl;
    }
    if (b < 0) return;                 // contiguous dead tail
    int nTj = (nv + JT - 1) / JT;
    int i0  = (local / nTj) * IC;
    int j0  = (local % nTj) * JT;

    int tid  = threadIdx.x;
    int lane = tid & 63;
    int w    = tid >> 6;          // wave 0..3
    int lg   = lane >> 4;         // k-slice group 0..3
    int lp   = lane & 15;         // pair col / row-within-group

    __shared__ uint4 W2s[64][16]; // 16 KB, unit-swizzled: [row][u ^ (row&15)]
    __shared__ uint4 Pl[IC][16];  // P rows (compacted) as f16 (8 KB)
    __shared__ int   iI[IC];      // original row index per compacted i

    {   // stage W2 (1024 uint4), coalesced global read, swizzled LDS write
        const uint4* W2v = (const uint4*)W2h;
#pragma unroll
        for (int q = 0; q < 4; ++q) {
            int m = tid + q * 256;
            int r = m >> 4, u = m & 15;
            W2s[r][u ^ (r & 15)] = W2v[m];
        }
    }
    {   // stage Pl: 16 rows x 16 chunks = 256 threads exactly
        int r = tid >> 4, c = tid & 15;
        int ir = i0 + r;
        int ivr = idx[b * N + (ir < nv ? ir : nv - 1)];
        if (c == 0) iI[r] = ivr;
        Pl[r][c] = *(const uint4*)(PQ + ((size_t)(b * N) + ivr) * 256 + c * 8);
    }
    __syncthreads();

    // per-c W2 read pointers: row = g*16+lp, unit = (c*4+lg)^lp; g via +g*256 units
    const uint4* pw0 = &W2s[lp][(0 * 4 + lg) ^ lp];
    const uint4* pw1 = &W2s[lp][(1 * 4 + lg) ^ lp];
    const uint4* pw2 = &W2s[lp][(2 * 4 + lg) ^ lp];
    const uint4* pw3 = &W2s[lp][(3 * 4 + lg) ^ lp];

    // Q fragments: lane's compacted pair jj = j0 + w*16 + lp
    int jj   = j0 + w * 16 + lp;
    bool jok = jj < nv;
    int jidx = idx[b * N + (jok ? jj : nv - 1)];
    F8 qf[4];
    {
        const _Float16* qrow = PQ + ((size_t)(b * N) + jidx) * 256 + 128;
#pragma unroll
        for (int c = 0; c < 4; ++c)
            qf[c].u = *(const uint4*)(qrow + c * 32 + lg * 8);
    }

    // epilogue constants
    f32x4 b2v[4];
#pragma unroll
    for (int g = 0; g < 4; ++g)
        b2v[g] = *(const f32x4*)(b2p + g * 16 + lg * 4);
    f16x8 w3f0 = *(const f16x8*)(w3h + lg * 8);
    f16x8 w3f1 = *(const f16x8*)(w3h + 32 + lg * 8);
    float b3s = b3v[0];
    const f32x4 z4 = 0.f;
    const f16x8 zh = (f16x8)(_Float16)0;

    size_t outbase = ((size_t)(b * N)) * N;

// dual-ii c-step: 4 W2 reads feed 8 MFMAs (accA + accB)
#define CSTEP2(IIA, IIB, C, PW)                                                \
    {                                                                          \
        F8 phA; phA.u = Pl[IIA][(C) * 4 + lg];                                 \
        F8 phB; phB.u = Pl[IIB][(C) * 4 + lg];                                 \
        f16x8 hvA = __builtin_elementwise_max(phA.f + qf[C].f, zh);            \
        f16x8 hvB = __builtin_elementwise_max(phB.f + qf[C].f, zh);            \
        F8 a0, a1, a2, a3;                                                     \
        a0.u = PW[0 * 256]; a1.u = PW[1 * 256];                                \
        a2.u = PW[2 * 256]; a3.u = PW[3 * 256];                                \
        accA[0] = __builtin_amdgcn_mfma_f32_16x16x32_f16(a0.f, hvA, accA[0], 0, 0, 0); \
        accB[0] = __builtin_amdgcn_mfma_f32_16x16x32_f16(a0.f, hvB, accB[0], 0, 0, 0); \
        accA[1] = __builtin_amdgcn_mfma_f32_16x16x32_f16(a1.f, hvA, accA[1], 0, 0, 0); \
        accB[1] = __builtin_amdgcn_mfma_f32_16x16x32_f16(a1.f, hvB, accB[1], 0, 0, 0); \
        accA[2] = __builtin_amdgcn_mfma_f32_16x16x32_f16(a2.f, hvA, accA[2], 0, 0, 0); \
        accB[2] = __builtin_amdgcn_mfma_f32_16x16x32_f16(a2.f, hvB, accB[2], 0, 0, 0); \
        accA[3] = __builtin_amdgcn_mfma_f32_16x16x32_f16(a3.f, hvA, accA[3], 0, 0, 0); \
        accB[3] = __builtin_amdgcn_mfma_f32_16x16x32_f16(a3.f, hvB, accB[3], 0, 0, 0); \
    }

// EPI computes the logit only (no exp/store) -> stored to logits[II] (static idx)
#define EPI(ACC, II)                                                           \
    {                                                                          \
        f32x4 t0 = __builtin_elementwise_max(ACC[0] + b2v[0], z4);             \
        f32x4 t1 = __builtin_elementwise_max(ACC[1] + b2v[1], z4);             \
        f32x4 t2 = __builtin_elementwise_max(ACC[2] + b2v[2], z4);             \
        f32x4 t3 = __builtin_elementwise_max(ACC[3] + b2v[3], z4);             \
        f16x8 h0, h1;                                                          \
        h0[0] = (_Float16)t0[0]; h0[1] = (_Float16)t0[1];                      \
        h0[2] = (_Float16)t0[2]; h0[3] = (_Float16)t0[3];                      \
        h0[4] = (_Float16)t1[0]; h0[5] = (_Float16)t1[1];                      \
        h0[6] = (_Float16)t1[2]; h0[7] = (_Float16)t1[3];                      \
        h1[0] = (_Float16)t2[0]; h1[1] = (_Float16)t2[1];                      \
        h1[2] = (_Float16)t2[2]; h1[3] = (_Float16)t2[3];                      \
        h1[4] = (_Float16)t3[0]; h1[5] = (_Float16)t3[1];                      \
        h1[6] = (_Float16)t3[2]; h1[7] = (_Float16)t3[3];                      \
        f32x4 rac0 = {b3s, b3s, b3s, b3s};                                     \
        f32x4 rac1 = 0.f;                                                      \
        rac0 = __builtin_amdgcn_mfma_f32_16x16x32_f16(w3f0, h0, rac0, 0, 0, 0);\
        rac1 = __builtin_amdgcn_mfma_f32_16x16x32_f16(w3f1, h1, rac1, 0, 0, 0);\
        logits[II] = rac0[0] + rac1[0];                                        \
    }

    float logits[IC];
    f32x4 accA[4], accB[4];
#pragma unroll
    for (int ii = 0; ii < IC; ii += 2) {
#pragma unroll
        for (int g = 0; g < 4; ++g) { accA[g] = 0.f; accB[g] = 0.f; }
        CSTEP2(ii, ii + 1, 0, pw0)
        CSTEP2(ii, ii + 1, 1, pw1)
        CSTEP2(ii, ii + 1, 2, pw2)
        CSTEP2(ii, ii + 1, 3, pw3)
        EPI(accA, ii)
        EPI(accB, ii + 1)
    }

    // deferred sigmoid + scattered stores (lane 0..15 of each wave)
    if (lane < 16 && jok) {
#pragma unroll
        for (int ii = 0; ii < IC; ++ii) {
            if (i0 + ii < nv) {
                float val = 1.f / (1.f + __expf(-logits[ii]));
                out[outbase + (size_t)iI[ii] * N + jidx] = val;
            }
        }
    }

#undef CSTEP2
#undef EPI
}

extern "C" void kernel_launch(void* const* d_in, const int* in_sizes, int n_in,
                              void* d_out, int out_size, void* d_ws, size_t ws_size,
                              hipStream_t stream) {
    const float* F0  = (const float*)d_in[0];
    const int*   msk = (const int*)  d_in[1];
    const float* W1  = (const float*)d_in[2];
    const float* b1  = (const float*)d_in[3];
    const float* W2  = (const float*)d_in[4];
    const float* b2  = (const float*)d_in[5];
    const float* W3  = (const float*)d_in[6];
    const float* b3  = (const float*)d_in[7];
    float* out = (float*)d_out;

    char* ws = (char*)d_ws;
    _Float16* PQ  = (_Float16*)ws;                                   // 2 MB
    _Float16* Wpq = (_Float16*)(ws + (2u << 20));                    // 64 KB
    _Float16* W2h = (_Float16*)(ws + (2u << 20) + (64u << 10));      // 16 KB
    float*    b1e = (float*)   (ws + (2u << 20) + (80u << 10));      // 1 KB
    float*    b2p = (float*)   (ws + (2u << 20) + (81u << 10));      // 256 B
    _Float16* w3h = (_Float16*)(ws + (2u << 20) + (82u << 10));      // 128 B
    int*      idx = (int*)     (ws + (2u << 20) + (84u << 10));      // 16 KB
    int*      cnt = (int*)     (ws + (2u << 20) + (100u << 10));     // 64 B

    // prep: zero output (masked pairs -> sigmoid(-1e9)==0), build weights, scan mask
    prep_kernel<<<NF + 64 + 8, 256, 0, stream>>>(W1, W2, b1, b2, W3, msk,
                                                 (float4*)out, Wpq, W2h, b1e, b2p,
                                                 w3h, idx, cnt);
    pq_mfma_kernel<<<dim3(B * N / 16, 4), 64, 0, stream>>>(F0, Wpq, b1e, PQ);

    int maxTiles = B * ((N + IC - 1) / IC) * ((N + JT - 1) / JT);    // 2048
    pair_mfma_kernel<<<maxTiles, 256, 0, stream>>>(
        PQ, W2h, b2p, w3h, b3, idx, cnt, out);
}

// Round 23
// 32.382 us; speedup vs baseline: 3.4267x; 1.1535x over previous
//
#include <hip/hip_runtime.h>

#define B 8
#define N 512
#define D 128
#define H 128
#define IC 16     // valid-i rows per block (pair kernel)
#define JT 64     // valid-j cols per block (4 waves x 16)
#define NF 1024   // fill blocks in prep kernel

typedef __attribute__((ext_vector_type(8))) _Float16 f16x8;
typedef __attribute__((ext_vector_type(2))) __fp16 fp16x2;
typedef __attribute__((ext_vector_type(4))) float f32x4;

union F8 { uint4 u; f16x8 f; };
union H8 { f16x8 f; fp16x2 p[4]; };

// W2-row permutation for the reduce-MFMA epilogue:
// pi(g,m) = (g>=2)*32 + (m>>2)*8 + (g&1)*4 + (m&3)
__device__ __host__ inline int w2perm(int g, int m) {
    return ((g >> 1) << 5) + ((m >> 2) << 3) + ((g & 1) << 2) + (m & 3);
}

// ---------------- kernel A: prep = fill(out) + build weights + scan ----------------
__global__ __launch_bounds__(256) void prep_kernel(
        const float* __restrict__ W1, const float* __restrict__ W2,
        const float* __restrict__ b1, const float* __restrict__ b2,
        const float* __restrict__ W3, const int* __restrict__ mask,
        float4* __restrict__ out4,
        _Float16* __restrict__ Wpq, _Float16* __restrict__ W2h,
        float* __restrict__ b1e, float* __restrict__ b2p,
        _Float16* __restrict__ w3h,
        int* __restrict__ idx, int* __restrict__ cnt) {
    int blk = blockIdx.x;
    int tid = threadIdx.x;
    if (blk < NF) {
        int base = blk * 512 + tid;
        out4[base]       = float4{0.f, 0.f, 0.f, 0.f};
        out4[base + 256] = float4{0.f, 0.f, 0.f, 0.f};
    } else if (blk < NF + 64) {
        int t = (blk - NF) * 256 + tid;   // 0 .. 16383
        if (t < H * D) {
            int h = t >> 7, k = t & 127;
            float wa = W1[h * 384 + k];
            float wb = W1[h * 384 + 128 + k];
            float wc = W1[h * 384 + 256 + k];
            Wpq[h * 128 + k]         = (_Float16)(wa + wc);
            Wpq[(128 + h) * 128 + k] = (_Float16)(wb - wc);
        }
        if (t < 64 * H) {   // permuted W2 rows
            int on = t >> 7, k = t & 127;
            int pi = w2perm(on >> 4, on & 15);
            W2h[t] = (_Float16)W2[pi * 128 + k];
        }
        if (t < 256) b1e[t] = (t < 128) ? b1[t] : 0.f;
        if (t < 64) {
            int pi = w2perm(t >> 4, t & 15);
            b2p[t] = b2[pi];
            w3h[t] = (_Float16)W3[t];
        }
    } else {
        int b = blk - NF - 64;
        int lane = tid;
        if (lane >= 64) return;
        const int* m = mask + b * N;
        int base = 0;
        for (int ch = 0; ch < N / 64; ++ch) {
            int v = m[ch * 64 + lane];
            unsigned long long bal = __ballot(v != 0);
            int pos = base + __popcll(bal & ((1ull << lane) - 1ull));
            if (v) idx[b * N + pos] = ch * 64 + lane;
            base += __popcll(bal);
        }
        if (lane == 0) cnt[b] = base;
    }
}

// ---------------- kernel 2: PQ = f16( F0 @ Wpq^T + b1e ), coalesced stores ----------------
__global__ __launch_bounds__(64) void pq_mfma_kernel(const float* __restrict__ F0,
                                                     const _Float16* __restrict__ Wpq,
                                                     const float* __restrict__ b1e,
                                                     _Float16* __restrict__ PQ) {
    int r0 = blockIdx.x * 16;        // F0 row base
    int cb = blockIdx.y * 64;        // output col base
    int lane = threadIdx.x;
    int lp = lane & 15, lg = lane >> 4;

    __shared__ _Float16 T[16][64];   // 2 KB transpose staging

    f16x8 af[4];
    const float* fr = F0 + (size_t)(r0 + lp) * D;
#pragma unroll
    for (int ks = 0; ks < 4; ++ks) {
        float4 a0 = *(const float4*)(fr + ks * 32 + lg * 8);
        float4 a1 = *(const float4*)(fr + ks * 32 + lg * 8 + 4);
        f16x8 v;
        v[0] = (_Float16)a0.x; v[1] = (_Float16)a0.y;
        v[2] = (_Float16)a0.z; v[3] = (_Float16)a0.w;
        v[4] = (_Float16)a1.x; v[5] = (_Float16)a1.y;
        v[6] = (_Float16)a1.z; v[7] = (_Float16)a1.w;
        af[ks] = v;
    }

#pragma unroll
    for (int ct = 0; ct < 4; ++ct) {
        int col = cb + ct * 16 + lp;
        const _Float16* wrow = Wpq + (size_t)col * 128;
        f32x4 acc = 0.f;
#pragma unroll
        for (int ks = 0; ks < 4; ++ks) {
            f16x8 bf = *(const f16x8*)(wrow + ks * 32 + lg * 8);
            acc = __builtin_amdgcn_mfma_f32_16x16x32_f16(af[ks], bf, acc, 0, 0, 0);
        }
        float b1v = b1e[col];
#pragma unroll
        for (int e = 0; e < 4; ++e)
            T[lg * 4 + e][ct * 16 + lp] = (_Float16)(acc[e] + b1v);
    }
    __syncthreads();

    // coalesced store: 4 lanes per row, 32B each -> 128B/row contiguous
    int r  = lane >> 2;
    int c4 = (lane & 3) * 16;
    uint4 v0 = *(const uint4*)&T[r][c4];
    uint4 v1 = *(const uint4*)&T[r][c4 + 8];
    _Float16* dst = PQ + (size_t)(r0 + r) * 256 + cb + c4;
    *(uint4*)dst       = v0;
    *(uint4*)(dst + 8) = v1;
}

// ---------------- kernel 3: fused pair MLP; W2 in swizzled LDS; dual-ii; IC=16 ----------------
// (256,3): proven no-spill operating point ((256,4) spills -- R8/R17/R20).
// R19 structure; EPI uses packed v_cvt_pkrtz (8 insts vs 16 scalar cvt).
__global__ __launch_bounds__(256, 3) void pair_mfma_kernel(
        const _Float16* __restrict__ PQ,
        const _Float16* __restrict__ W2h,
        const float* __restrict__ b2p, const _Float16* __restrict__ w3h,
        const float* __restrict__ b3v,
        const int* __restrict__ idx, const int* __restrict__ cnt,
        float* __restrict__ out) {
    int t = blockIdx.x;
    // map flat tile id -> (b, i0, j0) via per-batch tile counts from cnt[]
    int b = -1, local = 0, nv = 0, acc = 0;
#pragma unroll
    for (int k = 0; k < B; ++k) {
        int c   = cnt[k];
        int nTi = (c + IC - 1) / IC;
        int nTj = (c + JT - 1) / JT;
        int tl  = nTi * nTj;
        if (b < 0 && t < acc + tl) { b = k; local = t - acc; nv = c; }
        acc += tl;
    }
    if (b < 0) return;                 // contiguous dead tail
    int nTj = (nv + JT - 1) / JT;
    int i0  = (local / nTj) * IC;
    int j0  = (local % nTj) * JT;

    int tid  = threadIdx.x;
    int lane = tid & 63;
    int w    = tid >> 6;          // wave 0..3
    int lg   = lane >> 4;         // k-slice group 0..3
    int lp   = lane & 15;         // pair col / row-within-group

    __shared__ uint4 W2s[64][16]; // 16 KB, unit-swizzled: [row][u ^ (row&15)]
    __shared__ uint4 Pl[IC][16];  // P rows (compacted) as f16 (8 KB)
    __shared__ int   iI[IC];      // original row index per compacted i

    {   // stage W2 (1024 uint4), coalesced global read, swizzled LDS write
        const uint4* W2v = (const uint4*)W2h;
#pragma unroll
        for (int q = 0; q < 4; ++q) {
            int m = tid + q * 256;
            int r = m >> 4, u = m & 15;
            W2s[r][u ^ (r & 15)] = W2v[m];
        }
    }
    {   // stage Pl: 16 rows x 16 chunks = 256 threads exactly
        int r = tid >> 4, c = tid & 15;
        int ir = i0 + r;
        int ivr = idx[b * N + (ir < nv ? ir : nv - 1)];
        if (c == 0) iI[r] = ivr;
        Pl[r][c] = *(const uint4*)(PQ + ((size_t)(b * N) + ivr) * 256 + c * 8);
    }
    __syncthreads();

    // per-c W2 read pointers: row = g*16+lp, unit = (c*4+lg)^lp; g via +g*256 units
    const uint4* pw0 = &W2s[lp][(0 * 4 + lg) ^ lp];
    const uint4* pw1 = &W2s[lp][(1 * 4 + lg) ^ lp];
    const uint4* pw2 = &W2s[lp][(2 * 4 + lg) ^ lp];
    const uint4* pw3 = &W2s[lp][(3 * 4 + lg) ^ lp];

    // Q fragments: lane's compacted pair jj = j0 + w*16 + lp
    int jj   = j0 + w * 16 + lp;
    bool jok = jj < nv;
    int jidx = idx[b * N + (jok ? jj : nv - 1)];
    F8 qf[4];
    {
        const _Float16* qrow = PQ + ((size_t)(b * N) + jidx) * 256 + 128;
#pragma unroll
        for (int c = 0; c < 4; ++c)
            qf[c].u = *(const uint4*)(qrow + c * 32 + lg * 8);
    }

    // epilogue constants
    f32x4 b2v[4];
#pragma unroll
    for (int g = 0; g < 4; ++g)
        b2v[g] = *(const f32x4*)(b2p + g * 16 + lg * 4);
    f16x8 w3f0 = *(const f16x8*)(w3h + lg * 8);
    f16x8 w3f1 = *(const f16x8*)(w3h + 32 + lg * 8);
    float b3s = b3v[0];
    const f32x4 z4 = 0.f;
    const f16x8 zh = (f16x8)(_Float16)0;

    size_t outbase = ((size_t)(b * N)) * N;

// dual-ii c-step: 4 W2 reads feed 8 MFMAs (accA + accB)
#define CSTEP2(IIA, IIB, C, PW)                                                \
    {                                                                          \
        F8 phA; phA.u = Pl[IIA][(C) * 4 + lg];                                 \
        F8 phB; phB.u = Pl[IIB][(C) * 4 + lg];                                 \
        f16x8 hvA = __builtin_elementwise_max(phA.f + qf[C].f, zh);            \
        f16x8 hvB = __builtin_elementwise_max(phB.f + qf[C].f, zh);            \
        F8 a0, a1, a2, a3;                                                     \
        a0.u = PW[0 * 256]; a1.u = PW[1 * 256];                                \
        a2.u = PW[2 * 256]; a3.u = PW[3 * 256];                                \
        accA[0] = __builtin_amdgcn_mfma_f32_16x16x32_f16(a0.f, hvA, accA[0], 0, 0, 0); \
        accB[0] = __builtin_amdgcn_mfma_f32_16x16x32_f16(a0.f, hvB, accB[0], 0, 0, 0); \
        accA[1] = __builtin_amdgcn_mfma_f32_16x16x32_f16(a1.f, hvA, accA[1], 0, 0, 0); \
        accB[1] = __builtin_amdgcn_mfma_f32_16x16x32_f16(a1.f, hvB, accB[1], 0, 0, 0); \
        accA[2] = __builtin_amdgcn_mfma_f32_16x16x32_f16(a2.f, hvA, accA[2], 0, 0, 0); \
        accB[2] = __builtin_amdgcn_mfma_f32_16x16x32_f16(a2.f, hvB, accB[2], 0, 0, 0); \
        accA[3] = __builtin_amdgcn_mfma_f32_16x16x32_f16(a3.f, hvA, accA[3], 0, 0, 0); \
        accB[3] = __builtin_amdgcn_mfma_f32_16x16x32_f16(a3.f, hvB, accB[3], 0, 0, 0); \
    }

// EPI: packed f32->f16 cvt (v_cvt_pkrtz, 8 insts vs 16 scalar);
// independent reduce-MFMAs (rac0 || rac1), summed at the end.
#define EPI(ACC, II)                                                           \
    {                                                                          \
        f32x4 t0 = __builtin_elementwise_max(ACC[0] + b2v[0], z4);             \
        f32x4 t1 = __builtin_elementwise_max(ACC[1] + b2v[1], z4);             \
        f32x4 t2 = __builtin_elementwise_max(ACC[2] + b2v[2], z4);             \
        f32x4 t3 = __builtin_elementwise_max(ACC[3] + b2v[3], z4);             \
        H8 h0, h1;                                                             \
        h0.p[0] = __builtin_amdgcn_cvt_pkrtz(t0[0], t0[1]);                    \
        h0.p[1] = __builtin_amdgcn_cvt_pkrtz(t0[2], t0[3]);                    \
        h0.p[2] = __builtin_amdgcn_cvt_pkrtz(t1[0], t1[1]);                    \
        h0.p[3] = __builtin_amdgcn_cvt_pkrtz(t1[2], t1[3]);                    \
        h1.p[0] = __builtin_amdgcn_cvt_pkrtz(t2[0], t2[1]);                    \
        h1.p[1] = __builtin_amdgcn_cvt_pkrtz(t2[2], t2[3]);                    \
        h1.p[2] = __builtin_amdgcn_cvt_pkrtz(t3[0], t3[1]);                    \
        h1.p[3] = __builtin_amdgcn_cvt_pkrtz(t3[2], t3[3]);                    \
        f32x4 rac0 = {b3s, b3s, b3s, b3s};                                     \
        f32x4 rac1 = 0.f;                                                      \
        rac0 = __builtin_amdgcn_mfma_f32_16x16x32_f16(w3f0, h0.f, rac0, 0, 0, 0); \
        rac1 = __builtin_amdgcn_mfma_f32_16x16x32_f16(w3f1, h1.f, rac1, 0, 0, 0); \
        float logit = rac0[0] + rac1[0];                                       \
        float val = 1.f / (1.f + __expf(-logit));                              \
        if (lane < 16 && jok && (i0 + (II)) < nv)                              \
            out[outbase + (size_t)iI[II] * N + jidx] = val;                    \
    }

    f32x4 accA[4], accB[4];
#pragma unroll 1
    for (int ii = 0; ii < IC; ii += 2) {
#pragma unroll
        for (int g = 0; g < 4; ++g) { accA[g] = 0.f; accB[g] = 0.f; }
        CSTEP2(ii, ii + 1, 0, pw0)
        CSTEP2(ii, ii + 1, 1, pw1)
        CSTEP2(ii, ii + 1, 2, pw2)
        CSTEP2(ii, ii + 1, 3, pw3)
        EPI(accA, ii)
        EPI(accB, ii + 1)
    }

#undef CSTEP2
#undef EPI
}

extern "C" void kernel_launch(void* const* d_in, const int* in_sizes, int n_in,
                              void* d_out, int out_size, void* d_ws, size_t ws_size,
                              hipStream_t stream) {
    const float* F0  = (const float*)d_in[0];
    const int*   msk = (const int*)  d_in[1];
    const float* W1  = (const float*)d_in[2];
    const float* b1  = (const float*)d_in[3];
    const float* W2  = (const float*)d_in[4];
    const float* b2  = (const float*)d_in[5];
    const float* W3  = (const float*)d_in[6];
    const float* b3  = (const float*)d_in[7];
    float* out = (float*)d_out;

    char* ws = (char*)d_ws;
    _Float16* PQ  = (_Float16*)ws;                                   // 2 MB
    _Float16* Wpq = (_Float16*)(ws + (2u << 20));                    // 64 KB
    _Float16* W2h = (_Float16*)(ws + (2u << 20) + (64u << 10));      // 16 KB
    float*    b1e = (float*)   (ws + (2u << 20) + (80u << 10));      // 1 KB
    float*    b2p = (float*)   (ws + (2u << 20) + (81u << 10));      // 256 B
    _Float16* w3h = (_Float16*)(ws + (2u << 20) + (82u << 10));      // 128 B
    int*      idx = (int*)     (ws + (2u << 20) + (84u << 10));      // 16 KB
    int*      cnt = (int*)     (ws + (2u << 20) + (100u << 10));     // 64 B

    // prep: zero output (masked pairs -> sigmoid(-1e9)==0), build weights, scan mask
    prep_kernel<<<NF + 64 + 8, 256, 0, stream>>>(W1, W2, b1, b2, W3, msk,
                                                 (float4*)out, Wpq, W2h, b1e, b2p,
                                                 w3h, idx, cnt);
    pq_mfma_kernel<<<dim3(B * N / 16, 4), 64, 0, stream>>>(F0, Wpq, b1e, PQ);

    int maxTiles = B * ((N + IC - 1) / IC) * ((N + JT - 1) / JT);    // 2048
    pair_mfma_kernel<<<maxTiles, 256, 0, stream>>>(
        PQ, W2h, b2p, w3h, b3, idx, cnt, out);
}